// Round 2
// baseline (2512.984 us; speedup 1.0000x reference)
//
#include <hip/hip_runtime.h>

// Detect whether neighbor_indices is int64 or int32.
// If int64 (values are atom ids < 2^31), every odd 32-bit word (high halves)
// is zero. For random int32 indices, the OR of 1024 odd words is nonzero
// with overwhelming probability.
__global__ void detect_idx64_kernel(const unsigned int* __restrict__ idx_u32,
                                    int* __restrict__ flag) {
    __shared__ int nonzero;
    if (threadIdx.x == 0) nonzero = 0;
    __syncthreads();
    unsigned int v = idx_u32[2 * (threadIdx.x +   0) + 1]
                   | idx_u32[2 * (threadIdx.x + 256) + 1]
                   | idx_u32[2 * (threadIdx.x + 512) + 1]
                   | idx_u32[2 * (threadIdx.x + 768) + 1];
    if (v != 0u) atomicAdd(&nonzero, 1);
    __syncthreads();
    if (threadIdx.x == 0) *flag = (nonzero == 0) ? 1 : 0;  // 1 => int64
}

// Scatter with output replication: block b adds into replica (b & rep_mask).
// Replicas are (mostly) XCD-local since consecutive blocks round-robin across
// the 8 XCDs -> atomic lines stay resident in one XCD's L2 instead of
// ping-ponging through the fabric coherence point.
__global__ __launch_bounds__(256) void edge_scatter_rep_kernel(
    const float4* __restrict__ charges,     // [N_ATOMS] rows of 4 floats
    const void*  __restrict__ idx,          // [N_EDGES][2] int32 or int64
    const float* __restrict__ dist,         // [N_EDGES]
    float*       __restrict__ reps,         // R replicas of out, pre-zeroed
    int rep_mask,                           // R-1 (R power of two; 0 = direct)
    int out_floats,                         // floats per replica (400000)
    const int*   __restrict__ flag64,
    int n_edges)
{
    int e = blockIdx.x * blockDim.x + threadIdx.x;
    if (e >= n_edges) return;

    float* out = reps + (size_t)(blockIdx.x & rep_mask) * out_floats;

    int ai, aj;
    if (*flag64) {
        const longlong2* p = (const longlong2*)idx;
        longlong2 v = p[e];                 // 16B coalesced
        ai = (int)v.x; aj = (int)v.y;
    } else {
        const int2* p = (const int2*)idx;
        int2 v = p[e];                      // 8B coalesced
        ai = v.x; aj = v.y;
    }

    float d = dist[e];
    // erfc(d / (sqrt(2)*SMEARING)) / d, with the final /2 folded in.
    float pot = 0.5f * erfcf(d * 0.70710678118654752440f) / d;

    float4 ci = charges[ai];                // L2/L3-resident gathers
    float4 cj = charges[aj];

    float* oi = out + (size_t)ai * 4;
    float* oj = out + (size_t)aj * 4;
    unsafeAtomicAdd(oi + 0, cj.x * pot);
    unsafeAtomicAdd(oi + 1, cj.y * pot);
    unsafeAtomicAdd(oi + 2, cj.z * pot);
    unsafeAtomicAdd(oi + 3, cj.w * pot);
    unsafeAtomicAdd(oj + 0, ci.x * pot);
    unsafeAtomicAdd(oj + 1, ci.y * pot);
    unsafeAtomicAdd(oj + 2, ci.z * pot);
    unsafeAtomicAdd(oj + 3, ci.w * pot);
}

// Sum the R replicas into d_out. One thread per float4 row.
__global__ __launch_bounds__(256) void reduce_reps_kernel(
    const float4* __restrict__ reps, float4* __restrict__ out,
    int n_rows, int R)
{
    int i = blockIdx.x * blockDim.x + threadIdx.x;
    if (i >= n_rows) return;
    float4 s = make_float4(0.f, 0.f, 0.f, 0.f);
    for (int r = 0; r < R; ++r) {
        float4 v = reps[(size_t)r * n_rows + i];
        s.x += v.x; s.y += v.y; s.z += v.z; s.w += v.w;
    }
    out[i] = s;
}

extern "C" void kernel_launch(void* const* d_in, const int* in_sizes, int n_in,
                              void* d_out, int out_size, void* d_ws, size_t ws_size,
                              hipStream_t stream) {
    const float4* charges = (const float4*)d_in[0];
    const void*   idx     = d_in[1];
    const float*  dist    = (const float*)d_in[2];
    int n_edges = in_sizes[2];              // == N_EDGES (distances count)

    int* flag = (int*)d_ws;
    float* reps = (float*)((char*)d_ws + 256);
    size_t rep_bytes = (size_t)out_size * sizeof(float);

    // Pick the largest power-of-two replica count that fits in d_ws.
    int R = 1;
    size_t avail = ws_size > 256 ? ws_size - 256 : 0;
    int maxR = (int)(avail / rep_bytes);
    for (int r = 8; r >= 2; r >>= 1) { if (maxR >= r) { R = r; break; } }

    detect_idx64_kernel<<<1, 256, 0, stream>>>((const unsigned int*)idx, flag);

    int blocks = (n_edges + 255) / 256;
    if (R >= 2) {
        hipMemsetAsync(reps, 0, (size_t)R * rep_bytes, stream);
        edge_scatter_rep_kernel<<<blocks, 256, 0, stream>>>(
            charges, idx, dist, reps, R - 1, out_size, flag, n_edges);
        int n_rows = out_size / 4;
        reduce_reps_kernel<<<(n_rows + 255) / 256, 256, 0, stream>>>(
            (const float4*)reps, (float4*)d_out, n_rows, R);
    } else {
        hipMemsetAsync(d_out, 0, rep_bytes, stream);
        edge_scatter_rep_kernel<<<blocks, 256, 0, stream>>>(
            charges, idx, dist, (float*)d_out, 0, out_size, flag, n_edges);
    }
}

// Round 4
// 546.841 us; speedup vs baseline: 4.5955x; 4.5955x over previous
//
#include <hip/hip_runtime.h>

#define TILE_ATOMS 8192
#define TILE_FLOATS (TILE_ATOMS * 4)   // 128 KB LDS
#define BLOCK 1024
#define CHUNKS 19                      // 13 tiles * 19 chunks = 247 blocks

// Detect whether neighbor_indices is int64 or int32 (odd u32 words all zero
// => int64 high halves). 4-byte flag handoff proved replay-safe in r1/r2.
__global__ void detect_idx64_kernel(const unsigned int* __restrict__ idx_u32,
                                    int* __restrict__ flag) {
    __shared__ int nonzero;
    if (threadIdx.x == 0) nonzero = 0;
    __syncthreads();
    unsigned int v = idx_u32[2 * (threadIdx.x +   0) + 1]
                   | idx_u32[2 * (threadIdx.x + 256) + 1]
                   | idx_u32[2 * (threadIdx.x + 512) + 1]
                   | idx_u32[2 * (threadIdx.x + 768) + 1];
    if (v != 0u) atomicAdd(&nonzero, 1);
    __syncthreads();
    if (threadIdx.x == 0) *flag = (nonzero == 0) ? 1 : 0;  // 1 => int64
}

// Fused: block (t,c) streams edge chunk c, LDS-accumulates contributions
// landing in atom tile t, then atomically adds its tile into d_out.
// No plain-store inter-kernel handoff: d_out is written with HW f32 atomics
// (memory-side, globally visible under graph replay — the r1/r2-proven path).
__global__ __launch_bounds__(BLOCK, 1) void fused_tile_kernel(
    const float4* __restrict__ charges,   // [n_atoms]
    const void*  __restrict__ idx,        // [n_edges][2] int32 or int64
    const float* __restrict__ dist,       // [n_edges]
    float*       __restrict__ out,        // [n_atoms*4], pre-zeroed
    const int*   __restrict__ flag64,
    int n_edges, int n_atoms, int epc)
{
    __shared__ float tile[TILE_FLOATS];
    int t = blockIdx.x / CHUNKS;
    int c = blockIdx.x - t * CHUNKS;
    int tbase = t * TILE_ATOMS;
    for (int i = threadIdx.x; i < TILE_FLOATS; i += BLOCK) tile[i] = 0.f;
    bool f64 = (*flag64 != 0);
    __syncthreads();

    int e0 = c * epc;
    int e1 = min(n_edges, e0 + epc);
    #pragma unroll 2
    for (int e = e0 + (int)threadIdx.x; e < e1; e += BLOCK) {
        int ai, aj;
        if (f64) {
            longlong2 v = ((const longlong2*)idx)[e];   // 16B coalesced
            ai = (int)v.x; aj = (int)v.y;
        } else {
            int2 v = ((const int2*)idx)[e];             // 8B coalesced
            ai = v.x; aj = v.y;
        }
        unsigned ri = (unsigned)(ai - tbase);
        unsigned rj = (unsigned)(aj - tbase);
        if (ri < TILE_ATOMS || rj < TILE_ATOMS) {
            float d = dist[e];
            float p = 0.5f * erfcf(d * 0.70710678118654752440f) / d;
            if (ri < TILE_ATOMS) {
                float4 cj = charges[aj];                // L2/L3-resident
                atomicAdd(&tile[ri * 4 + 0], cj.x * p);
                atomicAdd(&tile[ri * 4 + 1], cj.y * p);
                atomicAdd(&tile[ri * 4 + 2], cj.z * p);
                atomicAdd(&tile[ri * 4 + 3], cj.w * p);
            }
            if (rj < TILE_ATOMS) {
                float4 ci = charges[ai];
                atomicAdd(&tile[rj * 4 + 0], ci.x * p);
                atomicAdd(&tile[rj * 4 + 1], ci.y * p);
                atomicAdd(&tile[rj * 4 + 2], ci.z * p);
                atomicAdd(&tile[rj * 4 + 3], ci.w * p);
            }
        }
    }
    __syncthreads();

    // Flush LDS tile to global with HW atomics (<=19-way per-address).
    const float4* src = (const float4*)tile;
    for (int r = threadIdx.x; r < TILE_ATOMS; r += BLOCK) {
        int a = tbase + r;
        if (a >= n_atoms) break;                        // t=12 phantom rows
        float4 v = src[r];                              // ds_read_b128
        if (v.x != 0.f || v.y != 0.f || v.z != 0.f || v.w != 0.f) {
            float* o = out + (size_t)a * 4;
            unsafeAtomicAdd(o + 0, v.x);
            unsafeAtomicAdd(o + 1, v.y);
            unsafeAtomicAdd(o + 2, v.z);
            unsafeAtomicAdd(o + 3, v.w);
        }
    }
}

extern "C" void kernel_launch(void* const* d_in, const int* in_sizes, int n_in,
                              void* d_out, int out_size, void* d_ws, size_t ws_size,
                              hipStream_t stream) {
    const float4* charges = (const float4*)d_in[0];
    const void*   idx     = d_in[1];
    const float*  dist    = (const float*)d_in[2];
    int n_edges = in_sizes[2];
    int n_atoms = in_sizes[0] / 4;
    int ntiles  = (n_atoms + TILE_ATOMS - 1) / TILE_ATOMS;   // 13
    int epc     = (n_edges + CHUNKS - 1) / CHUNKS;
    int* flag   = (int*)d_ws;

    hipMemsetAsync(d_out, 0, (size_t)out_size * sizeof(float), stream);
    detect_idx64_kernel<<<1, 256, 0, stream>>>((const unsigned int*)idx, flag);
    fused_tile_kernel<<<ntiles * CHUNKS, BLOCK, 0, stream>>>(
        charges, idx, dist, (float*)d_out, flag, n_edges, n_atoms, epc);
}